// Round 7
// baseline (395.352 us; speedup 1.0000x reference)
//
#include <hip/hip_runtime.h>
#include <cstdint>

typedef _Float16 f16;
typedef uint32_t u32;
typedef f16 f16x2 __attribute__((ext_vector_type(2)));
typedef f16 f16x8 __attribute__((ext_vector_type(8)));
typedef float f32x4 __attribute__((ext_vector_type(4)));
typedef u32 u32x4 __attribute__((ext_vector_type(4)));

#define NROWS 32768   // B*S = 8*4096
#define D_IN 1024
#define M_DIM 512
#define NKEYS 4096
#define KTOP 8

__device__ __forceinline__ u32 umax32(u32 a, u32 b) { return a > b ? a : b; }
__device__ __forceinline__ u32 umin32(u32 a, u32 b) { return a < b ? a : b; }

// async global->LDS, 16B per lane. LDS dest is wave-uniform base + lane*16 (HW).
// Fragment-major trick (r6, zero conflicts): choose each lane's GLOBAL source so
// that its HW dest slot (lane*16) is exactly the MFMA operand that lane consumes.
__device__ __forceinline__ void gload_lds16(const void* src, void* dst) {
  __builtin_amdgcn_global_load_lds(
      (const __attribute__((address_space(1))) uint32_t*)src,
      (__attribute__((address_space(3))) uint32_t*)dst, 16, 0, 0);
}

// ---------------------------------------------------------------------------
// prep: fp32->fp16 conversions + weight transposes (LDS-tiled, coalesced)
// ---------------------------------------------------------------------------
__global__ void prep_kernel(const float* __restrict__ keys, const float* __restrict__ values,
                            const float* __restrict__ wq, const float* __restrict__ wo,
                            f16* __restrict__ keys_h, f16* __restrict__ values_h,
                            f16* __restrict__ wqT, f16* __restrict__ woT) {
  const int b = blockIdx.x, t = threadIdx.x;
  if (b < 2048) {
    const float* src = (b < 1024) ? keys : values;
    f16* dst = (b < 1024) ? keys_h : values_h;
    const int bb = b & 1023;
    const size_t base = (size_t)bb * 2048 + (size_t)t * 8;
    f32x4 a = *(const f32x4*)(src + base);
    f32x4 c2 = *(const f32x4*)(src + base + 4);
    f16x8 o;
    o[0] = (f16)a[0]; o[1] = (f16)a[1]; o[2] = (f16)a[2]; o[3] = (f16)a[3];
    o[4] = (f16)c2[0]; o[5] = (f16)c2[1]; o[6] = (f16)c2[2]; o[7] = (f16)c2[3];
    *(f16x8*)(dst + base) = o;
    return;
  }
  __shared__ float lds[64][65];
  if (b < 2176) {
    // wq: [1024 d][512 m] -> wqT [512 m][1024 d]
    const int tb = b - 2048;           // 0..127
    const int td = tb >> 3, tm = tb & 7;
#pragma unroll
    for (int p = 0; p < 16; ++p) {
      const int d_loc = p * 4 + (t >> 6), m_loc = t & 63;
      lds[d_loc][m_loc] = wq[(size_t)(td * 64 + d_loc) * 512 + tm * 64 + m_loc];
    }
    __syncthreads();
#pragma unroll
    for (int p = 0; p < 16; ++p) {
      const int m_loc = p * 4 + (t >> 6), d_loc = t & 63;
      wqT[(size_t)(tm * 64 + m_loc) * 1024 + td * 64 + d_loc] = (f16)lds[d_loc][m_loc];
    }
  } else {
    // wo: [512 m][1024 od] -> woT [1024 od][512 m]
    const int tb = b - 2176;           // 0..127
    const int tmm = tb >> 4, tod = tb & 15;
#pragma unroll
    for (int p = 0; p < 16; ++p) {
      const int m_loc = p * 4 + (t >> 6), od_loc = t & 63;
      lds[m_loc][od_loc] = wo[(size_t)(tmm * 64 + m_loc) * 1024 + tod * 64 + od_loc];
    }
    __syncthreads();
#pragma unroll
    for (int p = 0; p < 16; ++p) {
      const int od_loc = p * 4 + (t >> 6), m_loc = t & 63;
      woT[(size_t)(tod * 64 + od_loc) * 512 + tmm * 64 + m_loc] = (f16)lds[m_loc][od_loc];
    }
  }
}

// ---------------------------------------------------------------------------
// qproj: q[row][m] = sum_d query[row][d]*wq[d][m] + bq[m], fp16 out.
// Fragment-major LDS: 64 slices of 1KB, slice (g2,kk) holds A-frag for
// m-rows [mt*32+g2*16, +16) x dims [kk*32, +32). Lane (g,c) consumes
// A[c][g*8+:8] at slot lane*16 -> stage source = wqT[(mt*32+g2*16+c)*1024
// + kk*32 + g*8]. Zero bank conflicts, imm-offset ds_read. Same operand
// values/order as before -> bit-exact.
// ---------------------------------------------------------------------------
__global__ __launch_bounds__(256, 2) void qproj_kernel(
    const float* __restrict__ query, const f16* __restrict__ wqT,
    const float* __restrict__ bq, f16* __restrict__ q_out) {
  __shared__ f16 Atile[64 * 512];   // 64 KB = 64 x 1KB fragment slices
  const int tid = threadIdx.x;
  const int wave = tid >> 6, lane = tid & 63;
  const int g = lane >> 4, c = lane & 15;
  const int rowbase = blockIdx.x * 64 + wave * 16;
  const int row = rowbase + c;

  f16x8 Breg[32];
  {
    const float* qrow = query + (size_t)row * D_IN;
#pragma unroll
    for (int kk = 0; kk < 32; ++kk) {
      f32x4 lo = *(const f32x4*)(qrow + kk * 32 + g * 8);
      f32x4 hi = *(const f32x4*)(qrow + kk * 32 + g * 8 + 4);
      f16x8 v;
      v[0] = (f16)lo[0]; v[1] = (f16)lo[1]; v[2] = (f16)lo[2]; v[3] = (f16)lo[3];
      v[4] = (f16)hi[0]; v[5] = (f16)hi[1]; v[6] = (f16)hi[2]; v[7] = (f16)hi[3];
      Breg[kk] = v;
    }
  }

  const int laneoff = c * D_IN + g * 8;   // per-lane source offset (elements)
  const int g2 = wave >> 1, kkb = (wave & 1) * 16;   // wave's 16 slices

  for (int mt = 0; mt < 16; ++mt) {
    __syncthreads();
    {
      const f16* tsrc = wqT + (size_t)(mt * 32 + g2 * 16) * D_IN + laneoff;
      char* dbase = (char*)Atile + (g2 * 32 + kkb) * 1024;
#pragma unroll
      for (int i2 = 0; i2 < 16; ++i2)
        gload_lds16(tsrc + (kkb + i2) * 32, dbase + i2 * 1024);
    }
    asm volatile("s_waitcnt vmcnt(0)" ::: "memory");
    __syncthreads();

    f32x4 acc0 = {0.f, 0.f, 0.f, 0.f};
    f32x4 acc1 = {0.f, 0.f, 0.f, 0.f};
    const char* tb = (const char*)Atile + lane * 16;
#pragma unroll
    for (int kk = 0; kk < 32; ++kk) {
      f16x8 a0 = *(const f16x8*)(tb + kk * 1024);            // g2=0: m rows 0-15
      f16x8 a1 = *(const f16x8*)(tb + 32768 + kk * 1024);    // g2=1: m rows 16-31
      acc0 = __builtin_amdgcn_mfma_f32_16x16x32_f16(a0, Breg[kk], acc0, 0, 0, 0);
      acc1 = __builtin_amdgcn_mfma_f32_16x16x32_f16(a1, Breg[kk], acc1, 0, 0, 0);
    }

    f32x4 bq0 = *(const f32x4*)(bq + mt * 32 + g * 4);
    f32x4 bq1 = *(const f32x4*)(bq + mt * 32 + 16 + g * 4);
    f16* qp = q_out + (size_t)row * M_DIM + mt * 32 + g * 4;
    f16x2 p;
    p[0] = (f16)(acc0[0] + bq0[0]); p[1] = (f16)(acc0[1] + bq0[1]); *(f16x2*)(qp + 0) = p;
    p[0] = (f16)(acc0[2] + bq0[2]); p[1] = (f16)(acc0[3] + bq0[3]); *(f16x2*)(qp + 2) = p;
    p[0] = (f16)(acc1[0] + bq1[0]); p[1] = (f16)(acc1[1] + bq1[1]); *(f16x2*)(qp + 16) = p;
    p[0] = (f16)(acc1[2] + bq1[2]); p[1] = (f16)(acc1[3] + bq1[3]); *(f16x2*)(qp + 18) = p;
  }
}

// ---------------------------------------------------------------------------
// scores+topk over a HALF of the key range (2048 keys), 16x16x32 MFMA,
// 512-thread blocks (8 waves x 16 rows), grid 512 = 2 blk/CU = 4 waves/SIMD
// (r4's occupancy) + fragment-major LDS (r6's zero-conflict/zero-VALU reads).
// Buffer = 32 slices x 1KB: slice (g2,kk) = keys [kt*32+g2*16,+16) x dims
// [kk*32,+32). Wave w stages 4 slices (g2=w>>2, kk=(w&3)*4+i2) with per-lane
// source keys_h[(.. + c)*512 + kk*32 + g*8]. MFMA/topk identical to r4 ->
// bit-identical output.
// ---------------------------------------------------------------------------
__global__ __launch_bounds__(512, 4) void scores_topk_kernel(
    const f16* __restrict__ q, const f16* __restrict__ keys_h,
    u32* __restrict__ cand) {
  __shared__ f16 Ktile[2 * 32 * 512];   // 2 x 32 KB fragment-major
  const int tid = threadIdx.x;
  const int wave = tid >> 6, lane = tid & 63;
  const int g = lane >> 4, c = lane & 15;
  const int rb = blockIdx.x >> 1, half = blockIdx.x & 1;
  const int rowbase = rb * 128 + wave * 16;
  const int myrow = rowbase + c;
  const int keybase = half * 2048;

  f16x8 Breg[16];
  {
    const f16* qr = q + (size_t)myrow * M_DIM;
#pragma unroll
    for (int kk = 0; kk < 16; ++kk)
      Breg[kk] = *(const f16x8*)(qr + kk * 32 + g * 8);
  }

  u32 topE[KTOP], topO[KTOP];
#pragma unroll
  for (int j = 0; j < KTOP; ++j) { topE[j] = 0u; topO[j] = 0u; }

  const int laneoff = c * M_DIM + g * 8;        // per-lane source offset
  const int g2 = wave >> 2, kkb = (wave & 3) * 4;  // wave's 4 slices

  auto stage = [&](int buf, int kt) {
    const f16* tsrc = keys_h + (size_t)(keybase + kt * 32 + g2 * 16) * M_DIM + laneoff;
    char* dbase = (char*)Ktile + buf * 32768 + (g2 * 16 + kkb) * 1024;
#pragma unroll
    for (int i2 = 0; i2 < 4; ++i2)
      gload_lds16(tsrc + (kkb + i2) * 32, dbase + i2 * 1024);
  };

  stage(0, 0);
  asm volatile("s_waitcnt vmcnt(0)" ::: "memory");
  __syncthreads();

  const char* base_rd = (const char*)Ktile + lane * 16;

  for (int kt = 0; kt < 64; ++kt) {
    const int cur = kt & 1;
    if (kt < 63) stage(cur ^ 1, kt + 1);

    f32x4 acc0 = {0.f, 0.f, 0.f, 0.f};
    f32x4 acc1 = {0.f, 0.f, 0.f, 0.f};
    const char* tb = base_rd + cur * 32768;
    __builtin_amdgcn_s_setprio(1);
#pragma unroll
    for (int kk = 0; kk < 16; ++kk) {
      f16x8 a0 = *(const f16x8*)(tb + kk * 1024);           // keys kt*32+0..15
      f16x8 a1 = *(const f16x8*)(tb + 16384 + kk * 1024);   // keys kt*32+16..31
      acc0 = __builtin_amdgcn_mfma_f32_16x16x32_f16(a0, Breg[kk], acc0, 0, 0, 0);
      acc1 = __builtin_amdgcn_mfma_f32_16x16x32_f16(a1, Breg[kk], acc1, 0, 0, 0);
    }
    __builtin_amdgcn_s_setprio(0);

#pragma unroll
    for (int i = 0; i < 4; ++i) {
      {
        const float s = acc0[i];
        const u32 kidx = (u32)(keybase + kt * 32 + g * 4 + i);
        const int bi = __float_as_int(s);
        const u32 mono = (u32)bi ^ (u32)((bi >> 31) | 0x80000000);   // order-preserving
        u32 x = ((mono + 0x800u) & 0xFFFFF000u) | kidx;              // 20b score + 12b idx
#pragma unroll
        for (int j = 0; j < KTOP; ++j) { const u32 nt = umax32(topE[j], x); x = umin32(topE[j], x); topE[j] = nt; }
      }
      {
        const float s = acc1[i];
        const u32 kidx = (u32)(keybase + kt * 32 + 16 + g * 4 + i);
        const int bi = __float_as_int(s);
        const u32 mono = (u32)bi ^ (u32)((bi >> 31) | 0x80000000);
        u32 x = ((mono + 0x800u) & 0xFFFFF000u) | kidx;
#pragma unroll
        for (int j = 0; j < KTOP; ++j) { const u32 nt = umax32(topO[j], x); x = umin32(topO[j], x); topO[j] = nt; }
      }
    }

    asm volatile("s_waitcnt vmcnt(0)" ::: "memory");
    __syncthreads();
  }

  // merge odd chain into even chain (lane's exact top-8 over its 512 keys)
#pragma unroll
  for (int j = 0; j < KTOP; ++j) {
    u32 x = topO[j];
#pragma unroll
    for (int jj = 0; jj < KTOP; ++jj) { const u32 nt = umax32(topE[jj], x); x = umin32(topE[jj], x); topE[jj] = nt; }
  }
  // merge across the 4 g-lanes sharing row c (disjoint key subsets -> exact)
#pragma unroll
  for (int st = 16; st <= 32; st <<= 1) {
    u32 oth[KTOP];
#pragma unroll
    for (int j = 0; j < KTOP; ++j) oth[j] = (u32)__shfl((int)topE[j], lane ^ st);
#pragma unroll
    for (int j = 0; j < KTOP; ++j) {
      u32 x = oth[j];
#pragma unroll
      for (int jj = 0; jj < KTOP; ++jj) { const u32 nt = umax32(topE[jj], x); x = umin32(topE[jj], x); topE[jj] = nt; }
    }
  }

  if (g == 0) {
    u32* cp = cand + (size_t)myrow * 16 + half * 8;
    u32x4 a, b;
    a.x = topE[0]; a.y = topE[1]; a.z = topE[2]; a.w = topE[3];
    b.x = topE[4]; b.y = topE[5]; b.z = topE[6]; b.w = topE[7];
    *(u32x4*)(cp) = a;
    *(u32x4*)(cp + 4) = b;
  }
}

// ---------------------------------------------------------------------------
// merge halves + softmax + gather. (unchanged)
// ---------------------------------------------------------------------------
__global__ __launch_bounds__(256, 4) void merge_gather_kernel(
    const u32* __restrict__ cand, const f16* __restrict__ values_h,
    f16* __restrict__ mem_out) {
  const int tid = threadIdx.x;
  const int wave = tid >> 6, lane = tid & 63;
  const int rowbase = blockIdx.x * 32 + wave * 8;
  const int myrow = rowbase + (lane & 7);

  const u32* cp = cand + (size_t)myrow * 16;
  u32x4 a0 = *(const u32x4*)(cp);
  u32x4 a1 = *(const u32x4*)(cp + 4);
  u32x4 b0 = *(const u32x4*)(cp + 8);
  u32x4 b1 = *(const u32x4*)(cp + 12);
  u32 top[KTOP] = {a0.x, a0.y, a0.z, a0.w, a1.x, a1.y, a1.z, a1.w};
  u32 ins[KTOP] = {b0.x, b0.y, b0.z, b0.w, b1.x, b1.y, b1.z, b1.w};
#pragma unroll
  for (int j = 0; j < KTOP; ++j) {
    u32 x = ins[j];
#pragma unroll
    for (int jj = 0; jj < KTOP; ++jj) { const u32 nt = umax32(top[jj], x); x = umin32(top[jj], x); top[jj] = nt; }
  }

  float w[KTOP]; u32 idx[KTOP];
  {
    float s[KTOP];
#pragma unroll
    for (int j = 0; j < KTOP; ++j) {
      const u32 mono = top[j] & 0xFFFFF000u;
      const u32 bits = (mono & 0x80000000u) ? (mono ^ 0x80000000u) : ~mono;
      s[j] = __int_as_float(bits);
      idx[j] = top[j] & 0xFFFu;
    }
    const float m0 = s[0];
    float sum = 0.f;
#pragma unroll
    for (int j = 0; j < KTOP; ++j) { w[j] = __expf(s[j] - m0); sum += w[j]; }
    const float inv = 1.f / sum;
#pragma unroll
    for (int j = 0; j < KTOP; ++j) w[j] *= inv;
  }

  for (int r = 0; r < 8; ++r) {
    float acc2[8];
#pragma unroll
    for (int e = 0; e < 8; ++e) acc2[e] = 0.f;
#pragma unroll
    for (int j = 0; j < KTOP; ++j) {
      const u32 ix = (u32)__shfl((int)idx[j], r);
      const float wj = __shfl(w[j], r);
      const f16x8 v = *(const f16x8*)(values_h + (size_t)ix * M_DIM + lane * 8);
#pragma unroll
      for (int e = 0; e < 8; ++e) acc2[e] += wj * (float)v[e];
    }
    f16x8 o;
#pragma unroll
    for (int e = 0; e < 8; ++e) o[e] = (f16)acc2[e];
    *(f16x8*)(mem_out + (size_t)(rowbase + r) * M_DIM + lane * 8) = o;
  }
}

// ---------------------------------------------------------------------------
// outproj: out[row][od] = sum_m mem[row][m]*wo[m][od] + bo[od] + query[row][od]
// Fragment-major LDS (32 slices x 1KB), same transformation as qproj.
// ---------------------------------------------------------------------------
__global__ __launch_bounds__(256, 2) void outproj_kernel(
    const f16* __restrict__ mem_h, const f16* __restrict__ woT,
    const float* __restrict__ bo, const float* __restrict__ query,
    float* __restrict__ out) {
  __shared__ f16 Atile[32 * 512];   // 32 KB = 32 x 1KB fragment slices
  const int tid = threadIdx.x;
  const int wave = tid >> 6, lane = tid & 63;
  const int g = lane >> 4, c = lane & 15;
  const int rowbase = blockIdx.x * 64 + wave * 16;
  const int row = rowbase + c;

  f16x8 Breg[16];
  {
    const f16* mr = mem_h + (size_t)row * M_DIM;
#pragma unroll
    for (int kk = 0; kk < 16; ++kk)
      Breg[kk] = *(const f16x8*)(mr + kk * 32 + g * 8);
  }

  const int laneoff = c * M_DIM + g * 8;
  const int g2 = wave >> 1, kkb = (wave & 1) * 8;   // wave's 8 slices

  for (int mt = 0; mt < 32; ++mt) {
    __syncthreads();
    {
      const f16* tsrc = woT + (size_t)(mt * 32 + g2 * 16) * M_DIM + laneoff;
      char* dbase = (char*)Atile + (g2 * 16 + kkb) * 1024;
#pragma unroll
      for (int i2 = 0; i2 < 8; ++i2)
        gload_lds16(tsrc + (kkb + i2) * 32, dbase + i2 * 1024);
    }
    asm volatile("s_waitcnt vmcnt(0)" ::: "memory");
    __syncthreads();

    f32x4 acc0 = {0.f, 0.f, 0.f, 0.f};
    f32x4 acc1 = {0.f, 0.f, 0.f, 0.f};
    const char* tb = (const char*)Atile + lane * 16;
#pragma unroll
    for (int kk = 0; kk < 16; ++kk) {
      f16x8 a0 = *(const f16x8*)(tb + kk * 1024);            // od rows 0-15
      f16x8 a1 = *(const f16x8*)(tb + 16384 + kk * 1024);    // od rows 16-31
      acc0 = __builtin_amdgcn_mfma_f32_16x16x32_f16(a0, Breg[kk], acc0, 0, 0, 0);
      acc1 = __builtin_amdgcn_mfma_f32_16x16x32_f16(a1, Breg[kk], acc1, 0, 0, 0);
    }

    const int od0 = mt * 32 + g * 4;
    f32x4 bo0 = *(const f32x4*)(bo + od0);
    f32x4 bo1 = *(const f32x4*)(bo + od0 + 16);
    const float* qp = query + (size_t)row * D_IN + od0;
    f32x4 q0 = *(const f32x4*)(qp);
    f32x4 q1 = *(const f32x4*)(qp + 16);
    f32x4 o0, o1;
#pragma unroll
    for (int i = 0; i < 4; ++i) {
      o0[i] = acc0[i] + bo0[i] + q0[i];
      o1[i] = acc1[i] + bo1[i] + q1[i];
    }
    float* op = out + (size_t)row * D_IN + od0;
    *(f32x4*)(op) = o0;
    *(f32x4*)(op + 16) = o1;
  }
}

extern "C" void kernel_launch(void* const* d_in, const int* in_sizes, int n_in,
                              void* d_out, int out_size, void* d_ws, size_t ws_size,
                              hipStream_t stream) {
  (void)in_sizes; (void)n_in; (void)out_size;
  const float* query = (const float*)d_in[0];
  const float* mkeys = (const float*)d_in[1];
  const float* mvals = (const float*)d_in[2];
  const float* wq    = (const float*)d_in[3];
  const float* bq    = (const float*)d_in[4];
  const float* wo    = (const float*)d_in[5];
  const float* bo    = (const float*)d_in[6];
  float* out = (float*)d_out;

  char* ws = (char*)d_ws;
  f16* keys_h   = (f16*)(ws);                                   //  4 MB
  f16* values_h = (f16*)(ws + (4u << 20));                      //  4 MB
  f16* wqT      = (f16*)(ws + (8u << 20));                      //  1 MB
  f16* woT      = (f16*)(ws + (9u << 20));                      //  1 MB
  f16* q_h      = (f16*)(ws + (10u << 20));                     // 32 MB
  f16* mem_h    = (f16*)(ws + (10u << 20) + (size_t)NROWS * M_DIM * 2);  // 32 MB
  u32* cand     = (u32*)(ws + (10u << 20) + 2ull * (size_t)NROWS * M_DIM * 2); // 2 MB
  const size_t need = (10u << 20) + 2ull * (size_t)NROWS * M_DIM * 2
                    + (size_t)NROWS * 16 * 4;
  if (ws_size < need) return;

  prep_kernel<<<2304, 256, 0, stream>>>(mkeys, mvals, wq, wo, keys_h, values_h, wqT, woT);
  qproj_kernel<<<NROWS / 64, 256, 0, stream>>>(query, wqT, bq, q_h);
  scores_topk_kernel<<<(NROWS / 128) * 2, 512, 0, stream>>>(q_h, keys_h, cand);
  merge_gather_kernel<<<NROWS / 32, 256, 0, stream>>>(cand, values_h, mem_h);
  outproj_kernel<<<NROWS / 64, 256, 0, stream>>>(mem_h, woT, bo, query, out);
}